// Round 8
// baseline (399.715 us; speedup 1.0000x reference)
//
#include <hip/hip_runtime.h>

// ---------------------------------------------------------------------------
// Cosine-attention transformer block, MI355X gfx950.  Round 8: col-major L2.
//
// R8 change vs R7 (one lever, isolated): block-index decomposition switched
// from x-major (bx fastest) to COLUMN-MAJOR (by fastest) under the same
// XCD-bijective chunking.  Each XCD chunk is now a bx-column: concurrent
// working set = 1 B panel (0.5-2 MB, stays L2-resident) + streaming A panels
// (A re-reads across columns served by L3; A fits 256MB L3).  R7 counters
// showed MLP2 FETCH=143.7MB vs 24MB unique (x-major put all gx B-panels
// ~8MB in every XCD's window > 4MB L2 -> B re-streamed per by-row).
//
// GEMM core (unchanged from R7): gemmra, BM=128/BN=256/BK=64, 8 waves 2Mx4N,
// DEPTH=2, 96 KB LDS, read-ahead-1 register pipeline:
//   iter t: stage(t+2, 6 gl_lds) -> vmcnt(6)=t+1 landed -> bar ->
//           read frags(t+1) (16 ds_read_b128) -> bar -> 32 MFMA on tile t regs.
//   Prologue: stage t0,t1; vmcnt(6); bar; read frags(t0); lgkmcnt(0);
//   sched_barrier; bar.  Tail: vmcnt(0) when staging stops.  NT even.
// XOR swizzle granule^=row&7 (T2); pre-swizzled gl_lds source (m173).
// ---------------------------------------------------------------------------

using u16 = unsigned short;
using bf16x8 = __attribute__((ext_vector_type(8))) __bf16;
using f32x4  = __attribute__((ext_vector_type(4))) float;

__device__ __forceinline__ u16 f2bf(float f) {
  unsigned u = __float_as_uint(f);
  unsigned r = (u + 0x7FFFu + ((u >> 16) & 1u)) >> 16;
  return (u16)r;
}
__device__ __forceinline__ float bf2f(u16 h) {
  return __uint_as_float(((unsigned)h) << 16);
}

// ---------------- fused fp32 -> bf16 cast (7 segments, one launch) ---------
struct CastSegs {
  const float* src[7];
  u16* dst[7];
  long beg[8];  // cumulative n4 boundaries
};
__global__ __launch_bounds__(256) void cast_multi_kernel(CastSegs cs) {
  long idx = (long)blockIdx.x * 256 + threadIdx.x;
  if (idx >= cs.beg[7]) return;
  int seg = 0;
#pragma unroll
  for (int s = 1; s < 7; ++s) seg += (idx >= cs.beg[s]) ? 1 : 0;
  const long loc = idx - cs.beg[seg];
  float4 v = reinterpret_cast<const float4*>(cs.src[seg])[loc];
  ushort4 o;
  o.x = f2bf(v.x); o.y = f2bf(v.y); o.z = f2bf(v.z); o.w = f2bf(v.w);
  reinterpret_cast<ushort4*>(cs.dst[seg])[loc] = o;
}

// ------- merged row L2-normalize: Q and K bf16 [8192][1024] -> bf16 --------
__global__ __launch_bounds__(256) void l2norm2_kernel(
    const u16* __restrict__ Qi, const u16* __restrict__ Ki,
    u16* __restrict__ Qo, u16* __restrict__ Ko) {
  __shared__ float red[4];
  long row = blockIdx.x;
  const u16* in;
  u16* out;
  if (row < 8192) { in = Qi + row * 1024; out = Qo + row * 1024; }
  else            { in = Ki + (row - 8192) * 1024; out = Ko + (row - 8192) * 1024; }
  const int tid = threadIdx.x, lane = tid & 63, wave = tid >> 6;
  ushort4 h = *reinterpret_cast<const ushort4*>(in + tid * 4);
  float x0 = bf2f(h.x), x1 = bf2f(h.y), x2 = bf2f(h.z), x3 = bf2f(h.w);
  float ss = x0 * x0 + x1 * x1 + x2 * x2 + x3 * x3;
#pragma unroll
  for (int o = 32; o; o >>= 1) ss += __shfl_xor(ss, o);
  if (lane == 0) red[wave] = ss;
  __syncthreads();
  ss = red[0] + red[1] + red[2] + red[3];
  float s = 1.0f / fmaxf(sqrtf(ss), 1e-12f);
  ushort4 o;
  o.x = f2bf(x0 * s); o.y = f2bf(x1 * s); o.z = f2bf(x2 * s); o.w = f2bf(x3 * s);
  *reinterpret_cast<ushort4*>(out + tid * 4) = o;
}

// ---------------- bf16 transpose: in [rows][cols] -> out [cols][rows] -------
__global__ void transpose_kernel(const u16* __restrict__ in, u16* __restrict__ out,
                                 int rows, int cols) {
  __shared__ u16 t[32][33];
  const int c0 = blockIdx.x * 32, r0 = blockIdx.y * 32;
  const long off = (long)blockIdx.z * rows * cols;
  const u16* ib = in + off;
  u16* ob = out + off;
  const int tx = threadIdx.x, ty = threadIdx.y;  // (32, 8)
#pragma unroll
  for (int j = 0; j < 4; ++j)
    t[ty + j * 8][tx] = ib[(long)(r0 + ty + j * 8) * cols + c0 + tx];
  __syncthreads();
#pragma unroll
  for (int j = 0; j < 4; ++j)
    ob[(long)(c0 + ty + j * 8) * rows + r0 + tx] = t[tx][ty + j * 8];
}

// ---------------- row softmax: bf16 [rows][2048] -> bf16 ----------------
__global__ __launch_bounds__(256) void softmax_kernel(
    const u16* __restrict__ in, u16* __restrict__ out) {
  __shared__ float red[4];
  long row = blockIdx.x;
  const int tid = threadIdx.x, lane = tid & 63, wave = tid >> 6;
  const u16* p = in + row * 2048 + tid * 8;
  ushort4 h0 = *reinterpret_cast<const ushort4*>(p);
  ushort4 h1 = *reinterpret_cast<const ushort4*>(p + 4);
  float v[8];
  v[0] = bf2f(h0.x); v[1] = bf2f(h0.y); v[2] = bf2f(h0.z); v[3] = bf2f(h0.w);
  v[4] = bf2f(h1.x); v[5] = bf2f(h1.y); v[6] = bf2f(h1.z); v[7] = bf2f(h1.w);
  float m = v[0];
#pragma unroll
  for (int i = 1; i < 8; ++i) m = fmaxf(m, v[i]);
#pragma unroll
  for (int o = 32; o; o >>= 1) m = fmaxf(m, __shfl_xor(m, o));
  if (lane == 0) red[wave] = m;
  __syncthreads();
  m = fmaxf(fmaxf(red[0], red[1]), fmaxf(red[2], red[3]));
  float s = 0.0f;
#pragma unroll
  for (int i = 0; i < 8; ++i) { v[i] = __expf(v[i] - m); s += v[i]; }
#pragma unroll
  for (int o = 32; o; o >>= 1) s += __shfl_xor(s, o);
  __syncthreads();
  if (lane == 0) red[wave] = s;
  __syncthreads();
  s = red[0] + red[1] + red[2] + red[3];
  float inv = 1.0f / s;
  ushort4 o0, o1;
  o0.x = f2bf(v[0] * inv); o0.y = f2bf(v[1] * inv);
  o0.z = f2bf(v[2] * inv); o0.w = f2bf(v[3] * inv);
  o1.x = f2bf(v[4] * inv); o1.y = f2bf(v[5] * inv);
  o1.z = f2bf(v[6] * inv); o1.w = f2bf(v[7] * inv);
  *reinterpret_cast<ushort4*>(out + row * 2048 + tid * 8) = o0;
  *reinterpret_cast<ushort4*>(out + row * 2048 + tid * 8 + 4) = o1;
}

// ---------------- RA1 bf16 NT GEMM ----------------
// C[m,n] = sum_k A[m,k]*B[n,k] (+bias[n]) (+relu).  BM=128, BN=256, BK=64.
// MODE: 0 = f32 out, 1 = bf16 out, 2 = QKV column-route (all bf16 out).
// Grid: 1-D of gx*gy*gz blocks, COLUMN-major (by fastest).  K%128==0, NT>=4.
struct Frags { bf16x8 a[4][2]; bf16x8 b[4][2]; };

template <int MODE>
__global__ __launch_bounds__(512, 2) void gemmra(
    const u16* __restrict__ A, const u16* __restrict__ Bw,
    const float* __restrict__ bias, void* __restrict__ Cout,
    const float* __restrict__ bias2, void* __restrict__ Cout2,
    const float* __restrict__ bias3, void* __restrict__ Cout3,
    int N, int K, long batchA, long batchB, long batchC, int relu,
    int gx, int gy) {
  constexpr int ASZ = 128 * 64;       // u16 per A buffer (16 KB)
  constexpr int BSZ = 256 * 64;       // u16 per B buffer (32 KB)
  __shared__ u16 lds[2 * (ASZ + BSZ)];  // 96 KB
  u16* const ldsA = lds;
  u16* const ldsB = lds + 2 * ASZ;

  // ---- XCD-bijective block swizzle (m204) ----
  const int nwg = gridDim.x;
  const int lid = blockIdx.x;
  const int q = nwg >> 3, r = nwg & 7;
  const int xcd = lid & 7, jj = lid >> 3;
  const int wg = (xcd < r ? xcd * (q + 1) : r * (q + 1) + (xcd - r) * q) + jj;
  // ---- COLUMN-major decomposition (R8): by fastest -> B panel L2-resident
  const int by = wg % gy;
  const int rest = wg / gy;
  const int bx = rest % gx;
  const int bz = rest / gx;

  const int tid = threadIdx.x, wave = tid >> 6, lane = tid & 63;
  const int wr = wave >> 2, wc = wave & 3;
  const int fr = lane & 15, hi = lane >> 4;

  const long Abase = bz * batchA + (long)by * 128 * K;
  const long Bbase = bz * batchB + (long)bx * 256 * K;

  // ---- swizzled ds_read offsets (u16 units) ----
  int aoff[4][2], boff[4][2];
#pragma unroll
  for (int m = 0; m < 4; ++m) {
    const int qm = m >> 1, ml = m & 1;
    const int row = qm * 64 + wr * 32 + ml * 16 + fr;
#pragma unroll
    for (int ks = 0; ks < 2; ++ks) {
      const int gg = ks * 4 + hi;
      aoff[m][ks] = row * 64 + ((gg ^ (row & 7)) * 8);
    }
  }
#pragma unroll
  for (int n = 0; n < 4; ++n) {
    const int qn = n >> 1, nl = n & 1;
    const int row = qn * 128 + wc * 32 + nl * 16 + fr;
#pragma unroll
    for (int ks = 0; ks < 2; ++ks) {
      const int gg = ks * 4 + hi;
      boff[n][ks] = row * 64 + ((gg ^ (row & 7)) * 8);
    }
  }

  // ---- stage source offsets (pre-swizzled global, m173) ----
  const int rA = wave * 8 + (lane >> 3);
  const int g8 = (((lane & 7) ^ (lane >> 3)) * 8);
  long asrc[2], bsrc[4];
#pragma unroll
  for (int rr = 0; rr < 2; ++rr) asrc[rr] = Abase + (long)(rr * 64 + rA) * K + g8;
#pragma unroll
  for (int rr = 0; rr < 4; ++rr) bsrc[rr] = Bbase + (long)(rr * 64 + rA) * K + g8;

#define STAGE_A(bufp, rr, k0)                                                  \
  __builtin_amdgcn_global_load_lds(                                            \
      (const __attribute__((address_space(1))) void*)(A + asrc[rr] + (k0)),    \
      (__attribute__((address_space(3))) void*)((bufp) + (rr) * 4096 + wave * 512), \
      16, 0, 0)
#define STAGE_B(bufp, rr, k0)                                                  \
  __builtin_amdgcn_global_load_lds(                                            \
      (const __attribute__((address_space(1))) void*)(Bw + bsrc[rr] + (k0)),   \
      (__attribute__((address_space(3))) void*)((bufp) + (rr) * 4096 + wave * 512), \
      16, 0, 0)
#define STAGE_TILE(T)                                                          \
  {                                                                            \
    u16* sA_ = ldsA + ((T) & 1) * ASZ;                                         \
    u16* sB_ = ldsB + ((T) & 1) * BSZ;                                         \
    const int k0_ = (T) << 6;                                                  \
    STAGE_A(sA_, 0, k0_); STAGE_A(sA_, 1, k0_);                                \
    STAGE_B(sB_, 0, k0_); STAGE_B(sB_, 1, k0_);                                \
    STAGE_B(sB_, 2, k0_); STAGE_B(sB_, 3, k0_);                                \
  }
#define READ_FRAGS(F, T)                                                       \
  {                                                                            \
    u16* rA_ = ldsA + ((T) & 1) * ASZ;                                         \
    u16* rB_ = ldsB + ((T) & 1) * BSZ;                                         \
    _Pragma("unroll") for (int m = 0; m < 4; ++m)                              \
    _Pragma("unroll") for (int ks = 0; ks < 2; ++ks)                           \
      F.a[m][ks] = *reinterpret_cast<const bf16x8*>(&rA_[aoff[m][ks]]);        \
    _Pragma("unroll") for (int n = 0; n < 4; ++n)                              \
    _Pragma("unroll") for (int ks = 0; ks < 2; ++ks)                           \
      F.b[n][ks] = *reinterpret_cast<const bf16x8*>(&rB_[boff[n][ks]]);        \
  }
#define RA_ITER(T, FC, FN)                                                     \
  {                                                                            \
    if ((T) + 2 < NT) STAGE_TILE((T) + 2)                                      \
    if ((T) + 1 < NT) {                                                        \
      if ((T) + 2 < NT) asm volatile("s_waitcnt vmcnt(6)" ::: "memory");       \
      else              asm volatile("s_waitcnt vmcnt(0)" ::: "memory");       \
      __builtin_amdgcn_s_barrier();                                            \
      READ_FRAGS(FN, (T) + 1)                                                  \
      __builtin_amdgcn_s_barrier();                                            \
    }                                                                          \
    __builtin_amdgcn_s_setprio(1);                                             \
    _Pragma("unroll") for (int ks = 0; ks < 2; ++ks)                           \
    _Pragma("unroll") for (int m = 0; m < 4; ++m)                              \
    _Pragma("unroll") for (int n = 0; n < 4; ++n)                              \
      acc[m][n] = __builtin_amdgcn_mfma_f32_16x16x32_bf16(                     \
          FC.a[m][ks], FC.b[n][ks], acc[m][n], 0, 0, 0);                       \
    __builtin_amdgcn_s_setprio(0);                                             \
  }

  const int NT = K >> 6;  // even, >=4 for all shapes used

  f32x4 acc[4][4] = {};
  Frags fA, fB;

  // ---- prologue: stage t0,t1; t0 landed; read frags(t0); reads complete ----
  STAGE_TILE(0)
  STAGE_TILE(1)
  asm volatile("s_waitcnt vmcnt(6)" ::: "memory");  // t0 landed
  __builtin_amdgcn_s_barrier();
  READ_FRAGS(fA, 0)
  asm volatile("s_waitcnt lgkmcnt(0)" ::: "memory");  // frags(t0) in regs
  __builtin_amdgcn_sched_barrier(0);
  __builtin_amdgcn_s_barrier();  // all waves done reading buf0 before ITER0 stages tile2 there

  for (int t = 0; t < NT; t += 2) {
    RA_ITER(t, fA, fB)
    RA_ITER(t + 1, fB, fA)
  }
#undef STAGE_A
#undef STAGE_B
#undef STAGE_TILE
#undef READ_FRAGS
#undef RA_ITER

  // ---- epilogue ----
  const long cbase = bz * batchC;
  const int crow = by * 128;
  int ccol = bx * 256;
  const float* bp = bias;
  void* cp = Cout;
  constexpr bool obf = (MODE == 1) || (MODE == 2);
  int Nst = N;
  if constexpr (MODE == 2) {
    const int sel = ccol >> 10;  // block-uniform
    if (sel == 1) { bp = bias2; cp = Cout2; }
    else if (sel == 2) { bp = bias3; cp = Cout3; }
    ccol &= 1023;
    Nst = 1024;
  }
#pragma unroll
  for (int m = 0; m < 4; ++m) {
    const int qm = m >> 1, ml = m & 1;
    const int r0 = crow + qm * 64 + wr * 32 + ml * 16 + hi * 4;
#pragma unroll
    for (int n = 0; n < 4; ++n) {
      const int qn = n >> 1, nl = n & 1;
      const int c = ccol + qn * 128 + wc * 32 + nl * 16 + fr;
      const float bb = bp ? bp[c] : 0.0f;
#pragma unroll
      for (int j = 0; j < 4; ++j) {
        float v = acc[m][n][j] + bb;
        if (relu) v = fmaxf(v, 0.0f);
        const long idx = cbase + (long)(r0 + j) * Nst + c;
        if (obf) ((u16*)cp)[idx] = f2bf(v);
        else     ((float*)cp)[idx] = v;
      }
    }
  }
}

// ---------------------------------------------------------------------------
extern "C" void kernel_launch(void* const* d_in, const int* in_sizes, int n_in,
                              void* d_out, int out_size, void* d_ws, size_t ws_size,
                              hipStream_t stream) {
  (void)in_sizes; (void)n_in; (void)out_size; (void)ws_size;
  const float* x  = (const float*)d_in[0];
  const float* Wq = (const float*)d_in[1];
  const float* bq = (const float*)d_in[2];
  const float* Wk = (const float*)d_in[3];
  const float* bk = (const float*)d_in[4];
  const float* Wv = (const float*)d_in[5];
  const float* bv = (const float*)d_in[6];
  const float* W1 = (const float*)d_in[7];
  const float* b1 = (const float*)d_in[8];
  const float* W2 = (const float*)d_in[9];
  const float* b2 = (const float*)d_in[10];
  const float* W3 = (const float*)d_in[11];
  const float* b3 = (const float*)d_in[12];

  char* ws = (char*)d_ws;
  const size_t MB = 1u << 20;
  // region 0
  u16* Qbf  = (u16*)(ws + 0);
  u16* Kbf  = Qbf + 8388608;
  u16* h2   = (u16*)(ws + 0);
  // region 1
  u16* xbf = (u16*)(ws + 64 * MB);
  u16* Vbf = xbf + (size_t)8192 * 1024;
  u16* P   = (u16*)(ws + 64 * MB);  // [4][2048][2048] bf16 = 32 MB
  // region 2 (weights, persistent)
  u16* Wq_b = (u16*)(ws + 96 * MB);   // Wq,Wk,Wv contiguous -> [3072][1024]
  u16* Wk_b = Wq_b + 1048576;
  u16* Wv_b = Wk_b + 1048576;
  u16* W1_b = Wv_b + 1048576;
  u16* W2_b = W1_b + 1048576;
  u16* W3_b = W2_b + 4194304;
  // region 3
  u16* Qn = (u16*)(ws + 120 * MB);
  u16* Kn = Qn + 8388608;
  u16* Vt = Kn + 8388608;
  u16* attnout = Qn;  // Qn dead after sim GEMM
  u16* h1      = Kn;  // Kn dead after sim GEMM

  // 1. fused casts (x + 6 weights), one launch
  CastSegs cs;
  cs.src[0] = x;  cs.dst[0] = xbf;
  cs.src[1] = Wq; cs.dst[1] = Wq_b;
  cs.src[2] = Wk; cs.dst[2] = Wk_b;
  cs.src[3] = Wv; cs.dst[3] = Wv_b;
  cs.src[4] = W1; cs.dst[4] = W1_b;
  cs.src[5] = W2; cs.dst[5] = W2_b;
  cs.src[6] = W3; cs.dst[6] = W3_b;
  long szs[7] = {2097152, 262144, 262144, 262144, 262144, 1048576, 1048576};
  long acc0 = 0;
  for (int i = 0; i < 7; ++i) { cs.beg[i] = acc0; acc0 += szs[i]; }
  cs.beg[7] = acc0;
  cast_multi_kernel<<<dim3((unsigned)((acc0 + 255) / 256)), 256, 0, stream>>>(cs);

  // 2. fused QKV: M=8192, N=3072, K=1024 (grid 12x64=768)
  gemmra<2><<<dim3(12 * 64), 512, 0, stream>>>(
      xbf, Wq_b, bq, Qbf, bk, Kbf, bv, Vbf, 3072, 1024, 0, 0, 0, 0, 12, 64);
  // 3. normalize (one launch) + transpose
  l2norm2_kernel<<<16384, 256, 0, stream>>>(Qbf, Kbf, Qn, Kn);
  transpose_kernel<<<dim3(32, 64, 4), dim3(32, 8), 0, stream>>>(Vbf, Vt, 2048, 1024);
  // 4. sim = Qn @ Kn^T per batch -> bf16 P-logits (grid 8x16x4=512)
  gemmra<1><<<dim3(8 * 16 * 4), 512, 0, stream>>>(
      Qn, Kn, nullptr, P, nullptr, nullptr, nullptr, nullptr,
      2048, 1024, 2097152L, 2097152L, 4194304L, 0, 8, 16);
  // 5. softmax (bf16 in/out), in-place on P
  softmax_kernel<<<8192, 256, 0, stream>>>(P, P);
  // 6. attnout = P @ V (M=2048, N=1024, K=2048, per batch; grid 4x16x4=256)
  gemmra<1><<<dim3(4 * 16 * 4), 512, 0, stream>>>(
      P, Vt, nullptr, attnout, nullptr, nullptr, nullptr, nullptr,
      1024, 2048, 4194304L, 2097152L, 2097152L, 0, 4, 16);
  // 7. MLP
  gemmra<1><<<dim3(4 * 64), 512, 0, stream>>>(
      attnout, W1_b, b1, h1, nullptr, nullptr, nullptr, nullptr,
      1024, 1024, 0, 0, 0, 1, 4, 64);
  gemmra<1><<<dim3(16 * 64), 512, 0, stream>>>(
      h1, W2_b, b2, h2, nullptr, nullptr, nullptr, nullptr,
      4096, 1024, 0, 0, 0, 1, 16, 64);
  gemmra<0><<<dim3(4 * 64), 512, 0, stream>>>(
      h2, W3_b, b3, (float*)d_out, nullptr, nullptr, nullptr, nullptr,
      1024, 4096, 0, 0, 0, 0, 4, 64);
}

// Round 9
// 370.105 us; speedup vs baseline: 1.0800x; 1.0800x over previous
//
#include <hip/hip_runtime.h>

// ---------------------------------------------------------------------------
// Cosine-attention transformer block, MI355X gfx950.  Round 9: m201 port.
//
// NEW: gemm256 — the guide's verified 256x256/8-phase structure (1563 TF@4k).
//   BM=BN=256, BK=64, 512 thr = 8 waves (2M x 4N), per-wave C 128x64,
//   LDS 2 x (A[256][64] + B[256][64]) = 128 KB, XOR-swizzle granule^=row&7.
//   Tile t lives in buf[t&1]; stage of tile t+2 targets the SAME buffer.
//
//   Phases (snake, frag-once with holds; in-phase read->MFMA like m201):
//     P0: read a0(8),b0(4);                bar; lgkm0; MFMA q00(a0,b0); bar
//     P1: read b1(4);  stage Ah0(t+2);     bar; lgkm0; MFMA q01(a0,b1); bar
//     P2: read a1(8);  stage Bh0(t+2);     bar; lgkm0; MFMA q11(a1,b1); bar
//     P3:              stage Ah1+Bh1(t+2);              MFMA q10(a1,b0);
//                      vmcnt(8 | 0 at tail); bar
//   Overwrite safety: each region's stage is issued only after the end
//   barrier of the phase that last ds_reads it (Ah0 read P0 -> staged P1;
//   Bh0 read P0, held in regs for P3 -> staged P2; Ah1 read P2 -> P3;
//   Bh1 read P1 -> P3).  Writes to buf[t&1] from iter t-2 all retired by
//   P3(t-1)'s vmcnt(8) (the 8 newest = iter t-1's stages, which target the
//   OTHER buffer).  vmcnt(8) at P3(t) leaves exactly iter-t's 8 stages in
//   flight -> tile t+1 fully landed before P0(t+1) reads (2-K-tile slack).
//   Prologue stages tiles 0,1 (16 loads); vmcnt(8)=tile0 landed; barrier.
//   lgkmcnt(0)+sched_barrier(0) pins read->MFMA order (rule #18).
//
// gemm256 used for: QKV (384 blk), sim (256), MLP2 (512).
// gemmra (R7 RA1 128x256 template, unchanged) for: PV, MLP1, MLP3.
// ---------------------------------------------------------------------------

using u16 = unsigned short;
using bf16x8 = __attribute__((ext_vector_type(8))) __bf16;
using f32x4  = __attribute__((ext_vector_type(4))) float;

__device__ __forceinline__ u16 f2bf(float f) {
  unsigned u = __float_as_uint(f);
  unsigned r = (u + 0x7FFFu + ((u >> 16) & 1u)) >> 16;
  return (u16)r;
}
__device__ __forceinline__ float bf2f(u16 h) {
  return __uint_as_float(((unsigned)h) << 16);
}

// ---------------- fused fp32 -> bf16 cast (7 segments, one launch) ---------
struct CastSegs {
  const float* src[7];
  u16* dst[7];
  long beg[8];
};
__global__ __launch_bounds__(256) void cast_multi_kernel(CastSegs cs) {
  long idx = (long)blockIdx.x * 256 + threadIdx.x;
  if (idx >= cs.beg[7]) return;
  int seg = 0;
#pragma unroll
  for (int s = 1; s < 7; ++s) seg += (idx >= cs.beg[s]) ? 1 : 0;
  const long loc = idx - cs.beg[seg];
  float4 v = reinterpret_cast<const float4*>(cs.src[seg])[loc];
  ushort4 o;
  o.x = f2bf(v.x); o.y = f2bf(v.y); o.z = f2bf(v.z); o.w = f2bf(v.w);
  reinterpret_cast<ushort4*>(cs.dst[seg])[loc] = o;
}

// ------- merged row L2-normalize: Q and K bf16 [8192][1024] -> bf16 --------
__global__ __launch_bounds__(256) void l2norm2_kernel(
    const u16* __restrict__ Qi, const u16* __restrict__ Ki,
    u16* __restrict__ Qo, u16* __restrict__ Ko) {
  __shared__ float red[4];
  long row = blockIdx.x;
  const u16* in;
  u16* out;
  if (row < 8192) { in = Qi + row * 1024; out = Qo + row * 1024; }
  else            { in = Ki + (row - 8192) * 1024; out = Ko + (row - 8192) * 1024; }
  const int tid = threadIdx.x, lane = tid & 63, wave = tid >> 6;
  ushort4 h = *reinterpret_cast<const ushort4*>(in + tid * 4);
  float x0 = bf2f(h.x), x1 = bf2f(h.y), x2 = bf2f(h.z), x3 = bf2f(h.w);
  float ss = x0 * x0 + x1 * x1 + x2 * x2 + x3 * x3;
#pragma unroll
  for (int o = 32; o; o >>= 1) ss += __shfl_xor(ss, o);
  if (lane == 0) red[wave] = ss;
  __syncthreads();
  ss = red[0] + red[1] + red[2] + red[3];
  float s = 1.0f / fmaxf(sqrtf(ss), 1e-12f);
  ushort4 o;
  o.x = f2bf(x0 * s); o.y = f2bf(x1 * s); o.z = f2bf(x2 * s); o.w = f2bf(x3 * s);
  *reinterpret_cast<ushort4*>(out + tid * 4) = o;
}

// ---------------- bf16 transpose: in [rows][cols] -> out [cols][rows] -------
__global__ void transpose_kernel(const u16* __restrict__ in, u16* __restrict__ out,
                                 int rows, int cols) {
  __shared__ u16 t[32][33];
  const int c0 = blockIdx.x * 32, r0 = blockIdx.y * 32;
  const long off = (long)blockIdx.z * rows * cols;
  const u16* ib = in + off;
  u16* ob = out + off;
  const int tx = threadIdx.x, ty = threadIdx.y;
#pragma unroll
  for (int j = 0; j < 4; ++j)
    t[ty + j * 8][tx] = ib[(long)(r0 + ty + j * 8) * cols + c0 + tx];
  __syncthreads();
#pragma unroll
  for (int j = 0; j < 4; ++j)
    ob[(long)(c0 + ty + j * 8) * rows + r0 + tx] = t[tx][ty + j * 8];
}

// ---------------- row softmax: bf16 [rows][2048] -> bf16 ----------------
__global__ __launch_bounds__(256) void softmax_kernel(
    const u16* __restrict__ in, u16* __restrict__ out) {
  __shared__ float red[4];
  long row = blockIdx.x;
  const int tid = threadIdx.x, lane = tid & 63, wave = tid >> 6;
  const u16* p = in + row * 2048 + tid * 8;
  ushort4 h0 = *reinterpret_cast<const ushort4*>(p);
  ushort4 h1 = *reinterpret_cast<const ushort4*>(p + 4);
  float v[8];
  v[0] = bf2f(h0.x); v[1] = bf2f(h0.y); v[2] = bf2f(h0.z); v[3] = bf2f(h0.w);
  v[4] = bf2f(h1.x); v[5] = bf2f(h1.y); v[6] = bf2f(h1.z); v[7] = bf2f(h1.w);
  float m = v[0];
#pragma unroll
  for (int i = 1; i < 8; ++i) m = fmaxf(m, v[i]);
#pragma unroll
  for (int o = 32; o; o >>= 1) m = fmaxf(m, __shfl_xor(m, o));
  if (lane == 0) red[wave] = m;
  __syncthreads();
  m = fmaxf(fmaxf(red[0], red[1]), fmaxf(red[2], red[3]));
  float s = 0.0f;
#pragma unroll
  for (int i = 0; i < 8; ++i) { v[i] = __expf(v[i] - m); s += v[i]; }
#pragma unroll
  for (int o = 32; o; o >>= 1) s += __shfl_xor(s, o);
  __syncthreads();
  if (lane == 0) red[wave] = s;
  __syncthreads();
  s = red[0] + red[1] + red[2] + red[3];
  float inv = 1.0f / s;
  ushort4 o0, o1;
  o0.x = f2bf(v[0] * inv); o0.y = f2bf(v[1] * inv);
  o0.z = f2bf(v[2] * inv); o0.w = f2bf(v[3] * inv);
  o1.x = f2bf(v[4] * inv); o1.y = f2bf(v[5] * inv);
  o1.z = f2bf(v[6] * inv); o1.w = f2bf(v[7] * inv);
  *reinterpret_cast<ushort4*>(out + row * 2048 + tid * 8) = o0;
  *reinterpret_cast<ushort4*>(out + row * 2048 + tid * 8 + 4) = o1;
}

// ======================= gemm256: 256x256 8-phase =========================
// C[m,n] = sum_k A[m,k]*B[n,k] (+bias) (+relu).  NT=K/64 >= 4.
// MODE: 0 f32 out, 1 bf16 out, 2 QKV column-route.  Grid 1-D, by fastest.
template <int MODE>
__global__ __launch_bounds__(512, 2) void gemm256(
    const u16* __restrict__ A, const u16* __restrict__ Bw,
    const float* __restrict__ bias, void* __restrict__ Cout,
    const float* __restrict__ bias2, void* __restrict__ Cout2,
    const float* __restrict__ bias3, void* __restrict__ Cout3,
    int N, int K, long batchA, long batchB, long batchC, int relu,
    int gx, int gy) {
  constexpr int ASZ = 256 * 64;  // 32 KB
  constexpr int BSZ = 256 * 64;
  __shared__ u16 lds[2 * (ASZ + BSZ)];  // 128 KB
  u16* const ldsA = lds;
  u16* const ldsB = lds + 2 * ASZ;

  const int nwg = gridDim.x;
  const int lid = blockIdx.x;
  const int q = nwg >> 3, r = nwg & 7;
  const int xcd = lid & 7, jj = lid >> 3;
  const int wg = (xcd < r ? xcd * (q + 1) : r * (q + 1) + (xcd - r) * q) + jj;
  const int by = wg % gy;
  const int rest = wg / gy;
  const int bx = rest % gx;
  const int bz = rest / gx;

  const int tid = threadIdx.x, wave = tid >> 6, lane = tid & 63;
  const int wr = wave >> 2, wc = wave & 3;
  const int fr = lane & 15, hi = lane >> 4;

  const long Abase = bz * batchA + (long)by * 256 * K;
  const long Bbase = bz * batchB + (long)bx * 256 * K;

  // swizzled ds_read offsets
  int aoff[2][4][2], boff[2][2][2];
#pragma unroll
  for (int qm = 0; qm < 2; ++qm)
#pragma unroll
    for (int ml = 0; ml < 4; ++ml) {
      const int row = qm * 128 + wr * 64 + ml * 16 + fr;
#pragma unroll
      for (int ks = 0; ks < 2; ++ks)
        aoff[qm][ml][ks] = row * 64 + (((ks * 4 + hi) ^ (row & 7)) * 8);
    }
#pragma unroll
  for (int qn = 0; qn < 2; ++qn)
#pragma unroll
    for (int nl = 0; nl < 2; ++nl) {
      const int row = qn * 128 + wc * 32 + nl * 16 + fr;
#pragma unroll
      for (int ks = 0; ks < 2; ++ks)
        boff[qn][nl][ks] = row * 64 + (((ks * 4 + hi) ^ (row & 7)) * 8);
    }

  // stage source offsets (pre-swizzled global, m173)
  const int rA = wave * 8 + (lane >> 3);
  const int g8 = (((lane & 7) ^ (lane >> 3)) * 8);
  long asrc[4], bsrc[4];
#pragma unroll
  for (int rr = 0; rr < 4; ++rr) {
    asrc[rr] = Abase + (long)(rr * 64 + rA) * K + g8;
    bsrc[rr] = Bbase + (long)(rr * 64 + rA) * K + g8;
  }

#define STAGE_A(bufp, rr, k0)                                                  \
  __builtin_amdgcn_global_load_lds(                                            \
      (const __attribute__((address_space(1))) void*)(A + asrc[rr] + (k0)),    \
      (__attribute__((address_space(3))) void*)((bufp) + (rr) * 4096 + wave * 512), \
      16, 0, 0)
#define STAGE_B(bufp, rr, k0)                                                  \
  __builtin_amdgcn_global_load_lds(                                            \
      (const __attribute__((address_space(1))) void*)(Bw + bsrc[rr] + (k0)),   \
      (__attribute__((address_space(3))) void*)((bufp) + (rr) * 4096 + wave * 512), \
      16, 0, 0)
#define MFMA_Q(ah, bh, qm, qn)                                                 \
  __builtin_amdgcn_s_setprio(1);                                               \
  _Pragma("unroll") for (int ks = 0; ks < 2; ++ks)                             \
  _Pragma("unroll") for (int ml = 0; ml < 4; ++ml)                             \
  _Pragma("unroll") for (int nl = 0; nl < 2; ++nl)                             \
    acc[(qm) * 4 + ml][(qn) * 2 + nl] =                                        \
        __builtin_amdgcn_mfma_f32_16x16x32_bf16(                               \
            ah[ml][ks], bh[nl][ks], acc[(qm) * 4 + ml][(qn) * 2 + nl], 0, 0, 0); \
  __builtin_amdgcn_s_setprio(0);
#define LGKM0                                                                  \
  asm volatile("s_waitcnt lgkmcnt(0)" ::: "memory");                           \
  __builtin_amdgcn_sched_barrier(0);

  const int NT = K >> 6;

  // prologue: stage tiles 0,1; tile0 landed; barrier
#pragma unroll
  for (int rr = 0; rr < 4; ++rr) { STAGE_A(ldsA, rr, 0); }
#pragma unroll
  for (int rr = 0; rr < 4; ++rr) { STAGE_B(ldsB, rr, 0); }
#pragma unroll
  for (int rr = 0; rr < 4; ++rr) { STAGE_A(ldsA + ASZ, rr, 64); }
#pragma unroll
  for (int rr = 0; rr < 4; ++rr) { STAGE_B(ldsB + BSZ, rr, 64); }
  asm volatile("s_waitcnt vmcnt(8)" ::: "memory");  // tile 0 landed
  __builtin_amdgcn_s_barrier();

  f32x4 acc[8][4] = {};

  for (int t = 0; t < NT; ++t) {
    u16* const cA = ldsA + (t & 1) * ASZ;
    u16* const cB = ldsB + (t & 1) * BSZ;
    const bool st = (t + 2) < NT;
    const int k2 = (t + 2) << 6;
    bf16x8 a0[4][2], a1[4][2], b0[2][2], b1[2][2];

    // ---- P0: read a0,b0 ; MFMA q00 ----
#pragma unroll
    for (int ml = 0; ml < 4; ++ml)
#pragma unroll
      for (int ks = 0; ks < 2; ++ks)
        a0[ml][ks] = *reinterpret_cast<const bf16x8*>(&cA[aoff[0][ml][ks]]);
#pragma unroll
    for (int nl = 0; nl < 2; ++nl)
#pragma unroll
      for (int ks = 0; ks < 2; ++ks)
        b0[nl][ks] = *reinterpret_cast<const bf16x8*>(&cB[boff[0][nl][ks]]);
    __builtin_amdgcn_s_barrier();
    LGKM0
    MFMA_Q(a0, b0, 0, 0)
    __builtin_amdgcn_s_barrier();

    // ---- P1: read b1 ; stage Ah0(t+2) ; MFMA q01 ----
#pragma unroll
    for (int nl = 0; nl < 2; ++nl)
#pragma unroll
      for (int ks = 0; ks < 2; ++ks)
        b1[nl][ks] = *reinterpret_cast<const bf16x8*>(&cB[boff[1][nl][ks]]);
    if (st) { STAGE_A(cA, 0, k2); STAGE_A(cA, 1, k2); }
    __builtin_amdgcn_s_barrier();
    LGKM0
    MFMA_Q(a0, b1, 0, 1)
    __builtin_amdgcn_s_barrier();

    // ---- P2: read a1 ; stage Bh0(t+2) ; MFMA q11 ----
#pragma unroll
    for (int ml = 0; ml < 4; ++ml)
#pragma unroll
      for (int ks = 0; ks < 2; ++ks)
        a1[ml][ks] = *reinterpret_cast<const bf16x8*>(&cA[aoff[1][ml][ks]]);
    if (st) { STAGE_B(cB, 0, k2); STAGE_B(cB, 1, k2); }
    __builtin_amdgcn_s_barrier();
    LGKM0
    MFMA_Q(a1, b1, 1, 1)
    __builtin_amdgcn_s_barrier();

    // ---- P3: stage Ah1,Bh1(t+2) ; MFMA q10 ; vmcnt ----
    if (st) {
      STAGE_A(cA, 2, k2); STAGE_A(cA, 3, k2);
      STAGE_B(cB, 2, k2); STAGE_B(cB, 3, k2);
    }
    MFMA_Q(a1, b0, 1, 0)
    if (st) asm volatile("s_waitcnt vmcnt(8)" ::: "memory");
    else    asm volatile("s_waitcnt vmcnt(0)" ::: "memory");
    __builtin_amdgcn_s_barrier();
  }
#undef STAGE_A
#undef STAGE_B
#undef MFMA_Q
#undef LGKM0

  // ---- epilogue ----
  const long cbase = bz * batchC;
  const int crow = by * 256;
  int ccol = bx * 256;
  const float* bp = bias;
  void* cp = Cout;
  constexpr bool obf = (MODE == 1) || (MODE == 2);
  int Nst = N;
  if constexpr (MODE == 2) {
    const int sel = ccol >> 10;
    if (sel == 1) { bp = bias2; cp = Cout2; }
    else if (sel == 2) { bp = bias3; cp = Cout3; }
    ccol &= 1023;
    Nst = 1024;
  }
#pragma unroll
  for (int qm = 0; qm < 2; ++qm)
#pragma unroll
    for (int ml = 0; ml < 4; ++ml) {
      const int r0 = crow + qm * 128 + wr * 64 + ml * 16 + hi * 4;
#pragma unroll
      for (int qn = 0; qn < 2; ++qn)
#pragma unroll
        for (int nl = 0; nl < 2; ++nl) {
          const int c = ccol + qn * 128 + wc * 32 + nl * 16 + fr;
          const float bb = bp ? bp[c] : 0.0f;
#pragma unroll
          for (int j = 0; j < 4; ++j) {
            float v = acc[qm * 4 + ml][qn * 2 + nl][j] + bb;
            if (relu) v = fmaxf(v, 0.0f);
            const long idx = cbase + (long)(r0 + j) * Nst + c;
            if (obf) ((u16*)cp)[idx] = f2bf(v);
            else     ((float*)cp)[idx] = v;
          }
        }
    }
}

// ======================= gemmra: RA1 128x256 (R7, unchanged) ===============
struct Frags { bf16x8 a[4][2]; bf16x8 b[4][2]; };

template <int MODE>
__global__ __launch_bounds__(512, 2) void gemmra(
    const u16* __restrict__ A, const u16* __restrict__ Bw,
    const float* __restrict__ bias, void* __restrict__ Cout,
    int N, int K, long batchA, long batchB, long batchC, int relu,
    int gx, int gy) {
  constexpr int ASZ = 128 * 64;
  constexpr int BSZ = 256 * 64;
  __shared__ u16 lds[2 * (ASZ + BSZ)];  // 96 KB
  u16* const ldsA = lds;
  u16* const ldsB = lds + 2 * ASZ;

  const int nwg = gridDim.x;
  const int lid = blockIdx.x;
  const int q = nwg >> 3, r = nwg & 7;
  const int xcd = lid & 7, jj = lid >> 3;
  const int wg = (xcd < r ? xcd * (q + 1) : r * (q + 1) + (xcd - r) * q) + jj;
  const int by = wg % gy;
  const int rest = wg / gy;
  const int bx = rest % gx;
  const int bz = rest / gx;

  const int tid = threadIdx.x, wave = tid >> 6, lane = tid & 63;
  const int wr = wave >> 2, wc = wave & 3;
  const int fr = lane & 15, hi = lane >> 4;

  const long Abase = bz * batchA + (long)by * 128 * K;
  const long Bbase = bz * batchB + (long)bx * 256 * K;

  int aoff[4][2], boff[4][2];
#pragma unroll
  for (int m = 0; m < 4; ++m) {
    const int qm = m >> 1, ml = m & 1;
    const int row = qm * 64 + wr * 32 + ml * 16 + fr;
#pragma unroll
    for (int ks = 0; ks < 2; ++ks)
      aoff[m][ks] = row * 64 + (((ks * 4 + hi) ^ (row & 7)) * 8);
  }
#pragma unroll
  for (int n = 0; n < 4; ++n) {
    const int qn = n >> 1, nl = n & 1;
    const int row = qn * 128 + wc * 32 + nl * 16 + fr;
#pragma unroll
    for (int ks = 0; ks < 2; ++ks)
      boff[n][ks] = row * 64 + (((ks * 4 + hi) ^ (row & 7)) * 8);
  }

  const int rA = wave * 8 + (lane >> 3);
  const int g8 = (((lane & 7) ^ (lane >> 3)) * 8);
  long asrc[2], bsrc[4];
#pragma unroll
  for (int rr = 0; rr < 2; ++rr) asrc[rr] = Abase + (long)(rr * 64 + rA) * K + g8;
#pragma unroll
  for (int rr = 0; rr < 4; ++rr) bsrc[rr] = Bbase + (long)(rr * 64 + rA) * K + g8;

#define STAGE_A(bufp, rr, k0)                                                  \
  __builtin_amdgcn_global_load_lds(                                            \
      (const __attribute__((address_space(1))) void*)(A + asrc[rr] + (k0)),    \
      (__attribute__((address_space(3))) void*)((bufp) + (rr) * 4096 + wave * 512), \
      16, 0, 0)
#define STAGE_B(bufp, rr, k0)                                                  \
  __builtin_amdgcn_global_load_lds(                                            \
      (const __attribute__((address_space(1))) void*)(Bw + bsrc[rr] + (k0)),   \
      (__attribute__((address_space(3))) void*)((bufp) + (rr) * 4096 + wave * 512), \
      16, 0, 0)
#define STAGE_TILE(T)                                                          \
  {                                                                            \
    u16* sA_ = ldsA + ((T) & 1) * ASZ;                                         \
    u16* sB_ = ldsB + ((T) & 1) * BSZ;                                         \
    const int k0_ = (T) << 6;                                                  \
    STAGE_A(sA_, 0, k0_); STAGE_A(sA_, 1, k0_);                                \
    STAGE_B(sB_, 0, k0_); STAGE_B(sB_, 1, k0_);                                \
    STAGE_B(sB_, 2, k0_); STAGE_B(sB_, 3, k0_);                                \
  }
#define READ_FRAGS(F, T)                                                       \
  {                                                                            \
    u16* rA_ = ldsA + ((T) & 1) * ASZ;                                         \
    u16* rB_ = ldsB + ((T) & 1) * BSZ;                                         \
    _Pragma("unroll") for (int m = 0; m < 4; ++m)                              \
    _Pragma("unroll") for (int ks = 0; ks < 2; ++ks)                           \
      F.a[m][ks] = *reinterpret_cast<const bf16x8*>(&rA_[aoff[m][ks]]);        \
    _Pragma("unroll") for (int n = 0; n < 4; ++n)                              \
    _Pragma("unroll") for (int ks = 0; ks < 2; ++ks)                           \
      F.b[n][ks] = *reinterpret_cast<const bf16x8*>(&rB_[boff[n][ks]]);        \
  }
#define RA_ITER(T, FC, FN)                                                     \
  {                                                                            \
    if ((T) + 2 < NT) STAGE_TILE((T) + 2)                                      \
    if ((T) + 1 < NT) {                                                        \
      if ((T) + 2 < NT) asm volatile("s_waitcnt vmcnt(6)" ::: "memory");       \
      else              asm volatile("s_waitcnt vmcnt(0)" ::: "memory");       \
      __builtin_amdgcn_s_barrier();                                            \
      READ_FRAGS(FN, (T) + 1)                                                  \
      __builtin_amdgcn_s_barrier();                                            \
    }                                                                          \
    __builtin_amdgcn_s_setprio(1);                                             \
    _Pragma("unroll") for (int ks = 0; ks < 2; ++ks)                           \
    _Pragma("unroll") for (int m = 0; m < 4; ++m)                              \
    _Pragma("unroll") for (int n = 0; n < 4; ++n)                              \
      acc[m][n] = __builtin_amdgcn_mfma_f32_16x16x32_bf16(                     \
          FC.a[m][ks], FC.b[n][ks], acc[m][n], 0, 0, 0);                       \
    __builtin_amdgcn_s_setprio(0);                                             \
  }

  const int NT = K >> 6;

  f32x4 acc[4][4] = {};
  Frags fA, fB;

  STAGE_TILE(0)
  STAGE_TILE(1)
  asm volatile("s_waitcnt vmcnt(6)" ::: "memory");
  __builtin_amdgcn_s_barrier();
  READ_FRAGS(fA, 0)
  asm volatile("s_waitcnt lgkmcnt(0)" ::: "memory");
  __builtin_amdgcn_sched_barrier(0);
  __builtin_amdgcn_s_barrier();

  for (int t = 0; t < NT; t += 2) {
    RA_ITER(t, fA, fB)
    RA_ITER(t + 1, fB, fA)
  }
#undef STAGE_A
#undef STAGE_B
#undef STAGE_TILE
#undef READ_FRAGS
#undef RA_ITER

  const long cbase = bz * batchC;
  const int crow = by * 128;
  const int ccol = bx * 256;
  constexpr bool obf = (MODE == 1);
#pragma unroll
  for (int m = 0; m < 4; ++m) {
    const int qm = m >> 1, ml = m & 1;
    const int r0 = crow + qm * 64 + wr * 32 + ml * 16 + hi * 4;
#pragma unroll
    for (int n = 0; n < 4; ++n) {
      const int qn = n >> 1, nl = n & 1;
      const int c = ccol + qn * 128 + wc * 32 + nl * 16 + fr;
      const float bb = bias ? bias[c] : 0.0f;
#pragma unroll
      for (int j = 0; j < 4; ++j) {
        float v = acc[m][n][j] + bb;
        if (relu) v = fmaxf(v, 0.0f);
        const long idx = cbase + (long)(r0 + j) * N + c;
        if (obf) ((u16*)Cout)[idx] = f2bf(v);
        else     ((float*)Cout)[idx] = v;
      }
    }
  }
}

// ---------------------------------------------------------------------------
extern "C" void kernel_launch(void* const* d_in, const int* in_sizes, int n_in,
                              void* d_out, int out_size, void* d_ws, size_t ws_size,
                              hipStream_t stream) {
  (void)in_sizes; (void)n_in; (void)out_size; (void)ws_size;
  const float* x  = (const float*)d_in[0];
  const float* Wq = (const float*)d_in[1];
  const float* bq = (const float*)d_in[2];
  const float* Wk = (const float*)d_in[3];
  const float* bk = (const float*)d_in[4];
  const float* Wv = (const float*)d_in[5];
  const float* bv = (const float*)d_in[6];
  const float* W1 = (const float*)d_in[7];
  const float* b1 = (const float*)d_in[8];
  const float* W2 = (const float*)d_in[9];
  const float* b2 = (const float*)d_in[10];
  const float* W3 = (const float*)d_in[11];
  const float* b3 = (const float*)d_in[12];

  char* ws = (char*)d_ws;
  const size_t MB = 1u << 20;
  u16* Qbf  = (u16*)(ws + 0);
  u16* Kbf  = Qbf + 8388608;
  u16* h2   = (u16*)(ws + 0);
  u16* xbf = (u16*)(ws + 64 * MB);
  u16* Vbf = xbf + (size_t)8192 * 1024;
  u16* P   = (u16*)(ws + 64 * MB);
  u16* Wq_b = (u16*)(ws + 96 * MB);
  u16* Wk_b = Wq_b + 1048576;
  u16* Wv_b = Wk_b + 1048576;
  u16* W1_b = Wv_b + 1048576;
  u16* W2_b = W1_b + 1048576;
  u16* W3_b = W2_b + 4194304;
  u16* Qn = (u16*)(ws + 120 * MB);
  u16* Kn = Qn + 8388608;
  u16* Vt = Kn + 8388608;
  u16* attnout = Qn;
  u16* h1      = Kn;

  CastSegs cs;
  cs.src[0] = x;  cs.dst[0] = xbf;
  cs.src[1] = Wq; cs.dst[1] = Wq_b;
  cs.src[2] = Wk; cs.dst[2] = Wk_b;
  cs.src[3] = Wv; cs.dst[3] = Wv_b;
  cs.src[4] = W1; cs.dst[4] = W1_b;
  cs.src[5] = W2; cs.dst[5] = W2_b;
  cs.src[6] = W3; cs.dst[6] = W3_b;
  long szs[7] = {2097152, 262144, 262144, 262144, 262144, 1048576, 1048576};
  long acc0 = 0;
  for (int i = 0; i < 7; ++i) { cs.beg[i] = acc0; acc0 += szs[i]; }
  cs.beg[7] = acc0;
  cast_multi_kernel<<<dim3((unsigned)((acc0 + 255) / 256)), 256, 0, stream>>>(cs);

  // 2. fused QKV: M=8192, N=3072, K=1024 (256^2, grid 12x32=384)
  gemm256<2><<<dim3(12 * 32), 512, 0, stream>>>(
      xbf, Wq_b, bq, Qbf, bk, Kbf, bv, Vbf, 3072, 1024, 0, 0, 0, 0, 12, 32);
  // 3. normalize + transpose
  l2norm2_kernel<<<16384, 256, 0, stream>>>(Qbf, Kbf, Qn, Kn);
  transpose_kernel<<<dim3(32, 64, 4), dim3(32, 8), 0, stream>>>(Vbf, Vt, 2048, 1024);
  // 4. sim = Qn @ Kn^T -> bf16 (256^2, grid 8x8x4=256)
  gemm256<1><<<dim3(8 * 8 * 4), 512, 0, stream>>>(
      Qn, Kn, nullptr, P, nullptr, nullptr, nullptr, nullptr,
      2048, 1024, 2097152L, 2097152L, 4194304L, 0, 8, 8);
  // 5. softmax (bf16 in/out), in-place on P
  softmax_kernel<<<8192, 256, 0, stream>>>(P, P);
  // 6. attnout = P @ V (gemmra, grid 4x16x4=256)
  gemmra<1><<<dim3(4 * 16 * 4), 512, 0, stream>>>(
      P, Vt, nullptr, attnout, 1024, 2048, 4194304L, 2097152L, 2097152L, 0, 4, 16);
  // 7. MLP
  gemmra<1><<<dim3(4 * 64), 512, 0, stream>>>(
      attnout, W1_b, b1, h1, 1024, 1024, 0, 0, 0, 1, 4, 64);
  gemm256<1><<<dim3(16 * 32), 512, 0, stream>>>(
      h1, W2_b, b2, h2, nullptr, nullptr, nullptr, nullptr,
      4096, 1024, 0, 0, 0, 1, 16, 32);
  gemmra<0><<<dim3(4 * 64), 512, 0, stream>>>(
      h2, W3_b, b3, (float*)d_out, 1024, 4096, 0, 0, 0, 0, 4, 64);
}

// Round 10
// 364.259 us; speedup vs baseline: 1.0973x; 1.0160x over previous
//
#include <hip/hip_runtime.h>

// ---------------------------------------------------------------------------
// Cosine-attention transformer block, MI355X gfx950.  Round 10: supertiling.
//
// R10 change vs R9 (one lever): block-index decomposition in BOTH GEMM
// templates becomes 2-D SUPERTILED: wg -> (bz, band, bx, byloc), byloc
// (size GBY) fastest.  Each XCD's concurrent window = GBY rows x several
// columns: B panels L2-resident AND the A-stripe (GBY x 0.5-1 MB) reused
// across all gx columns of the band.  L2-fill arithmetic per GEMM:
//   QKV  (12x32, GBY=8):  per band A 4MB+B 6MB;  4 bands  -> ~40MB (was 135)
//   sim  (8x8x4, GBY=8):  per batch A 4+B 4 (1 band)      -> ~32MB (was ~135)
//   MLP2 (16x32, GBY=8):  per band A 4+B 8;  4 bands      -> ~48MB (was 135)
//   MLP3 (4x64, GBY=16):  per band A 16+B 8; 4 bands      -> ~96MB (was ~190)
//   MLP1 (4x64, GBY=16), PV (4x16x4, GBY=8): similar reductions.
// GEMM cores (gemm256 8-phase, gemmra RA1) unchanged from R9.
// ---------------------------------------------------------------------------

using u16 = unsigned short;
using bf16x8 = __attribute__((ext_vector_type(8))) __bf16;
using f32x4  = __attribute__((ext_vector_type(4))) float;

__device__ __forceinline__ u16 f2bf(float f) {
  unsigned u = __float_as_uint(f);
  unsigned r = (u + 0x7FFFu + ((u >> 16) & 1u)) >> 16;
  return (u16)r;
}
__device__ __forceinline__ float bf2f(u16 h) {
  return __uint_as_float(((unsigned)h) << 16);
}

// Shared block-decomposition: XCD-bijective chunking (m204) then supertile.
__device__ __forceinline__ void decomp(int lid, int nwg, int gx, int gy,
                                       int gby, int& bx, int& by, int& bz) {
  const int q = nwg >> 3, r = nwg & 7;
  const int xcd = lid & 7, jj = lid >> 3;
  const int wg = (xcd < r ? xcd * (q + 1) : r * (q + 1) + (xcd - r) * q) + jj;
  const int byloc = wg % gby;
  const int t1 = wg / gby;
  bx = t1 % gx;
  const int t2 = t1 / gx;
  const int nb = gy / gby;
  const int band = t2 % nb;
  bz = t2 / nb;
  by = band * gby + byloc;
}

// ---------------- fused fp32 -> bf16 cast (7 segments, one launch) ---------
struct CastSegs {
  const float* src[7];
  u16* dst[7];
  long beg[8];
};
__global__ __launch_bounds__(256) void cast_multi_kernel(CastSegs cs) {
  long idx = (long)blockIdx.x * 256 + threadIdx.x;
  if (idx >= cs.beg[7]) return;
  int seg = 0;
#pragma unroll
  for (int s = 1; s < 7; ++s) seg += (idx >= cs.beg[s]) ? 1 : 0;
  const long loc = idx - cs.beg[seg];
  float4 v = reinterpret_cast<const float4*>(cs.src[seg])[loc];
  ushort4 o;
  o.x = f2bf(v.x); o.y = f2bf(v.y); o.z = f2bf(v.z); o.w = f2bf(v.w);
  reinterpret_cast<ushort4*>(cs.dst[seg])[loc] = o;
}

// ------- merged row L2-normalize: Q and K bf16 [8192][1024] -> bf16 --------
__global__ __launch_bounds__(256) void l2norm2_kernel(
    const u16* __restrict__ Qi, const u16* __restrict__ Ki,
    u16* __restrict__ Qo, u16* __restrict__ Ko) {
  __shared__ float red[4];
  long row = blockIdx.x;
  const u16* in;
  u16* out;
  if (row < 8192) { in = Qi + row * 1024; out = Qo + row * 1024; }
  else            { in = Ki + (row - 8192) * 1024; out = Ko + (row - 8192) * 1024; }
  const int tid = threadIdx.x, lane = tid & 63, wave = tid >> 6;
  ushort4 h = *reinterpret_cast<const ushort4*>(in + tid * 4);
  float x0 = bf2f(h.x), x1 = bf2f(h.y), x2 = bf2f(h.z), x3 = bf2f(h.w);
  float ss = x0 * x0 + x1 * x1 + x2 * x2 + x3 * x3;
#pragma unroll
  for (int o = 32; o; o >>= 1) ss += __shfl_xor(ss, o);
  if (lane == 0) red[wave] = ss;
  __syncthreads();
  ss = red[0] + red[1] + red[2] + red[3];
  float s = 1.0f / fmaxf(sqrtf(ss), 1e-12f);
  ushort4 o;
  o.x = f2bf(x0 * s); o.y = f2bf(x1 * s); o.z = f2bf(x2 * s); o.w = f2bf(x3 * s);
  *reinterpret_cast<ushort4*>(out + tid * 4) = o;
}

// ---------------- bf16 transpose: in [rows][cols] -> out [cols][rows] -------
__global__ void transpose_kernel(const u16* __restrict__ in, u16* __restrict__ out,
                                 int rows, int cols) {
  __shared__ u16 t[32][33];
  const int c0 = blockIdx.x * 32, r0 = blockIdx.y * 32;
  const long off = (long)blockIdx.z * rows * cols;
  const u16* ib = in + off;
  u16* ob = out + off;
  const int tx = threadIdx.x, ty = threadIdx.y;
#pragma unroll
  for (int j = 0; j < 4; ++j)
    t[ty + j * 8][tx] = ib[(long)(r0 + ty + j * 8) * cols + c0 + tx];
  __syncthreads();
#pragma unroll
  for (int j = 0; j < 4; ++j)
    ob[(long)(c0 + ty + j * 8) * rows + r0 + tx] = t[tx][ty + j * 8];
}

// ---------------- row softmax: bf16 [rows][2048] -> bf16 ----------------
__global__ __launch_bounds__(256) void softmax_kernel(
    const u16* __restrict__ in, u16* __restrict__ out) {
  __shared__ float red[4];
  long row = blockIdx.x;
  const int tid = threadIdx.x, lane = tid & 63, wave = tid >> 6;
  const u16* p = in + row * 2048 + tid * 8;
  ushort4 h0 = *reinterpret_cast<const ushort4*>(p);
  ushort4 h1 = *reinterpret_cast<const ushort4*>(p + 4);
  float v[8];
  v[0] = bf2f(h0.x); v[1] = bf2f(h0.y); v[2] = bf2f(h0.z); v[3] = bf2f(h0.w);
  v[4] = bf2f(h1.x); v[5] = bf2f(h1.y); v[6] = bf2f(h1.z); v[7] = bf2f(h1.w);
  float m = v[0];
#pragma unroll
  for (int i = 1; i < 8; ++i) m = fmaxf(m, v[i]);
#pragma unroll
  for (int o = 32; o; o >>= 1) m = fmaxf(m, __shfl_xor(m, o));
  if (lane == 0) red[wave] = m;
  __syncthreads();
  m = fmaxf(fmaxf(red[0], red[1]), fmaxf(red[2], red[3]));
  float s = 0.0f;
#pragma unroll
  for (int i = 0; i < 8; ++i) { v[i] = __expf(v[i] - m); s += v[i]; }
#pragma unroll
  for (int o = 32; o; o >>= 1) s += __shfl_xor(s, o);
  __syncthreads();
  if (lane == 0) red[wave] = s;
  __syncthreads();
  s = red[0] + red[1] + red[2] + red[3];
  float inv = 1.0f / s;
  ushort4 o0, o1;
  o0.x = f2bf(v[0] * inv); o0.y = f2bf(v[1] * inv);
  o0.z = f2bf(v[2] * inv); o0.w = f2bf(v[3] * inv);
  o1.x = f2bf(v[4] * inv); o1.y = f2bf(v[5] * inv);
  o1.z = f2bf(v[6] * inv); o1.w = f2bf(v[7] * inv);
  *reinterpret_cast<ushort4*>(out + row * 2048 + tid * 8) = o0;
  *reinterpret_cast<ushort4*>(out + row * 2048 + tid * 8 + 4) = o1;
}

// ======================= gemm256: 256x256 8-phase =========================
template <int MODE>
__global__ __launch_bounds__(512, 2) void gemm256(
    const u16* __restrict__ A, const u16* __restrict__ Bw,
    const float* __restrict__ bias, void* __restrict__ Cout,
    const float* __restrict__ bias2, void* __restrict__ Cout2,
    const float* __restrict__ bias3, void* __restrict__ Cout3,
    int N, int K, long batchA, long batchB, long batchC, int relu,
    int gx, int gy, int gby) {
  constexpr int ASZ = 256 * 64;
  constexpr int BSZ = 256 * 64;
  __shared__ u16 lds[2 * (ASZ + BSZ)];  // 128 KB
  u16* const ldsA = lds;
  u16* const ldsB = lds + 2 * ASZ;

  int bx, by, bz;
  decomp(blockIdx.x, gridDim.x, gx, gy, gby, bx, by, bz);

  const int tid = threadIdx.x, wave = tid >> 6, lane = tid & 63;
  const int wr = wave >> 2, wc = wave & 3;
  const int fr = lane & 15, hi = lane >> 4;

  const long Abase = bz * batchA + (long)by * 256 * K;
  const long Bbase = bz * batchB + (long)bx * 256 * K;

  int aoff[2][4][2], boff[2][2][2];
#pragma unroll
  for (int qm = 0; qm < 2; ++qm)
#pragma unroll
    for (int ml = 0; ml < 4; ++ml) {
      const int row = qm * 128 + wr * 64 + ml * 16 + fr;
#pragma unroll
      for (int ks = 0; ks < 2; ++ks)
        aoff[qm][ml][ks] = row * 64 + (((ks * 4 + hi) ^ (row & 7)) * 8);
    }
#pragma unroll
  for (int qn = 0; qn < 2; ++qn)
#pragma unroll
    for (int nl = 0; nl < 2; ++nl) {
      const int row = qn * 128 + wc * 32 + nl * 16 + fr;
#pragma unroll
      for (int ks = 0; ks < 2; ++ks)
        boff[qn][nl][ks] = row * 64 + (((ks * 4 + hi) ^ (row & 7)) * 8);
    }

  const int rA = wave * 8 + (lane >> 3);
  const int g8 = (((lane & 7) ^ (lane >> 3)) * 8);
  long asrc[4], bsrc[4];
#pragma unroll
  for (int rr = 0; rr < 4; ++rr) {
    asrc[rr] = Abase + (long)(rr * 64 + rA) * K + g8;
    bsrc[rr] = Bbase + (long)(rr * 64 + rA) * K + g8;
  }

#define STAGE_A(bufp, rr, k0)                                                  \
  __builtin_amdgcn_global_load_lds(                                            \
      (const __attribute__((address_space(1))) void*)(A + asrc[rr] + (k0)),    \
      (__attribute__((address_space(3))) void*)((bufp) + (rr) * 4096 + wave * 512), \
      16, 0, 0)
#define STAGE_B(bufp, rr, k0)                                                  \
  __builtin_amdgcn_global_load_lds(                                            \
      (const __attribute__((address_space(1))) void*)(Bw + bsrc[rr] + (k0)),   \
      (__attribute__((address_space(3))) void*)((bufp) + (rr) * 4096 + wave * 512), \
      16, 0, 0)
#define MFMA_Q(ah, bh, qm, qn)                                                 \
  __builtin_amdgcn_s_setprio(1);                                               \
  _Pragma("unroll") for (int ks = 0; ks < 2; ++ks)                             \
  _Pragma("unroll") for (int ml = 0; ml < 4; ++ml)                             \
  _Pragma("unroll") for (int nl = 0; nl < 2; ++nl)                             \
    acc[(qm) * 4 + ml][(qn) * 2 + nl] =                                        \
        __builtin_amdgcn_mfma_f32_16x16x32_bf16(                               \
            ah[ml][ks], bh[nl][ks], acc[(qm) * 4 + ml][(qn) * 2 + nl], 0, 0, 0); \
  __builtin_amdgcn_s_setprio(0);
#define LGKM0                                                                  \
  asm volatile("s_waitcnt lgkmcnt(0)" ::: "memory");                           \
  __builtin_amdgcn_sched_barrier(0);

  const int NT = K >> 6;

#pragma unroll
  for (int rr = 0; rr < 4; ++rr) { STAGE_A(ldsA, rr, 0); }
#pragma unroll
  for (int rr = 0; rr < 4; ++rr) { STAGE_B(ldsB, rr, 0); }
#pragma unroll
  for (int rr = 0; rr < 4; ++rr) { STAGE_A(ldsA + ASZ, rr, 64); }
#pragma unroll
  for (int rr = 0; rr < 4; ++rr) { STAGE_B(ldsB + BSZ, rr, 64); }
  asm volatile("s_waitcnt vmcnt(8)" ::: "memory");
  __builtin_amdgcn_s_barrier();

  f32x4 acc[8][4] = {};

  for (int t = 0; t < NT; ++t) {
    u16* const cA = ldsA + (t & 1) * ASZ;
    u16* const cB = ldsB + (t & 1) * BSZ;
    const bool st = (t + 2) < NT;
    const int k2 = (t + 2) << 6;
    bf16x8 a0[4][2], a1[4][2], b0[2][2], b1[2][2];

    // P0: read a0,b0 ; MFMA q00
#pragma unroll
    for (int ml = 0; ml < 4; ++ml)
#pragma unroll
      for (int ks = 0; ks < 2; ++ks)
        a0[ml][ks] = *reinterpret_cast<const bf16x8*>(&cA[aoff[0][ml][ks]]);
#pragma unroll
    for (int nl = 0; nl < 2; ++nl)
#pragma unroll
      for (int ks = 0; ks < 2; ++ks)
        b0[nl][ks] = *reinterpret_cast<const bf16x8*>(&cB[boff[0][nl][ks]]);
    __builtin_amdgcn_s_barrier();
    LGKM0
    MFMA_Q(a0, b0, 0, 0)
    __builtin_amdgcn_s_barrier();

    // P1: read b1 ; stage Ah0(t+2) ; MFMA q01
#pragma unroll
    for (int nl = 0; nl < 2; ++nl)
#pragma unroll
      for (int ks = 0; ks < 2; ++ks)
        b1[nl][ks] = *reinterpret_cast<const bf16x8*>(&cB[boff[1][nl][ks]]);
    if (st) { STAGE_A(cA, 0, k2); STAGE_A(cA, 1, k2); }
    __builtin_amdgcn_s_barrier();
    LGKM0
    MFMA_Q(a0, b1, 0, 1)
    __builtin_amdgcn_s_barrier();

    // P2: read a1 ; stage Bh0(t+2) ; MFMA q11
#pragma unroll
    for (int ml = 0; ml < 4; ++ml)
#pragma unroll
      for (int ks = 0; ks < 2; ++ks)
        a1[ml][ks] = *reinterpret_cast<const bf16x8*>(&cA[aoff[1][ml][ks]]);
    if (st) { STAGE_B(cB, 0, k2); STAGE_B(cB, 1, k2); }
    __builtin_amdgcn_s_barrier();
    LGKM0
    MFMA_Q(a1, b1, 1, 1)
    __builtin_amdgcn_s_barrier();

    // P3: stage Ah1,Bh1(t+2) ; MFMA q10 ; vmcnt
    if (st) {
      STAGE_A(cA, 2, k2); STAGE_A(cA, 3, k2);
      STAGE_B(cB, 2, k2); STAGE_B(cB, 3, k2);
    }
    MFMA_Q(a1, b0, 1, 0)
    if (st) asm volatile("s_waitcnt vmcnt(8)" ::: "memory");
    else    asm volatile("s_waitcnt vmcnt(0)" ::: "memory");
    __builtin_amdgcn_s_barrier();
  }
#undef STAGE_A
#undef STAGE_B
#undef MFMA_Q
#undef LGKM0

  const long cbase = bz * batchC;
  const int crow = by * 256;
  int ccol = bx * 256;
  const float* bp = bias;
  void* cp = Cout;
  constexpr bool obf = (MODE == 1) || (MODE == 2);
  int Nst = N;
  if constexpr (MODE == 2) {
    const int sel = ccol >> 10;
    if (sel == 1) { bp = bias2; cp = Cout2; }
    else if (sel == 2) { bp = bias3; cp = Cout3; }
    ccol &= 1023;
    Nst = 1024;
  }
#pragma unroll
  for (int qm = 0; qm < 2; ++qm)
#pragma unroll
    for (int ml = 0; ml < 4; ++ml) {
      const int r0 = crow + qm * 128 + wr * 64 + ml * 16 + hi * 4;
#pragma unroll
      for (int qn = 0; qn < 2; ++qn)
#pragma unroll
        for (int nl = 0; nl < 2; ++nl) {
          const int c = ccol + qn * 128 + wc * 32 + nl * 16 + fr;
          const float bb = bp ? bp[c] : 0.0f;
#pragma unroll
          for (int j = 0; j < 4; ++j) {
            float v = acc[qm * 4 + ml][qn * 2 + nl][j] + bb;
            if (relu) v = fmaxf(v, 0.0f);
            const long idx = cbase + (long)(r0 + j) * Nst + c;
            if (obf) ((u16*)cp)[idx] = f2bf(v);
            else     ((float*)cp)[idx] = v;
          }
        }
    }
}

// ======================= gemmra: RA1 128x256 ===============
struct Frags { bf16x8 a[4][2]; bf16x8 b[4][2]; };

template <int MODE>
__global__ __launch_bounds__(512, 2) void gemmra(
    const u16* __restrict__ A, const u16* __restrict__ Bw,
    const float* __restrict__ bias, void* __restrict__ Cout,
    int N, int K, long batchA, long batchB, long batchC, int relu,
    int gx, int gy, int gby) {
  constexpr int ASZ = 128 * 64;
  constexpr int BSZ = 256 * 64;
  __shared__ u16 lds[2 * (ASZ + BSZ)];  // 96 KB
  u16* const ldsA = lds;
  u16* const ldsB = lds + 2 * ASZ;

  int bx, by, bz;
  decomp(blockIdx.x, gridDim.x, gx, gy, gby, bx, by, bz);

  const int tid = threadIdx.x, wave = tid >> 6, lane = tid & 63;
  const int wr = wave >> 2, wc = wave & 3;
  const int fr = lane & 15, hi = lane >> 4;

  const long Abase = bz * batchA + (long)by * 128 * K;
  const long Bbase = bz * batchB + (long)bx * 256 * K;

  int aoff[4][2], boff[4][2];
#pragma unroll
  for (int m = 0; m < 4; ++m) {
    const int qm = m >> 1, ml = m & 1;
    const int row = qm * 64 + wr * 32 + ml * 16 + fr;
#pragma unroll
    for (int ks = 0; ks < 2; ++ks)
      aoff[m][ks] = row * 64 + (((ks * 4 + hi) ^ (row & 7)) * 8);
  }
#pragma unroll
  for (int n = 0; n < 4; ++n) {
    const int qn = n >> 1, nl = n & 1;
    const int row = qn * 128 + wc * 32 + nl * 16 + fr;
#pragma unroll
    for (int ks = 0; ks < 2; ++ks)
      boff[n][ks] = row * 64 + (((ks * 4 + hi) ^ (row & 7)) * 8);
  }

  const int rA = wave * 8 + (lane >> 3);
  const int g8 = (((lane & 7) ^ (lane >> 3)) * 8);
  long asrc[2], bsrc[4];
#pragma unroll
  for (int rr = 0; rr < 2; ++rr) asrc[rr] = Abase + (long)(rr * 64 + rA) * K + g8;
#pragma unroll
  for (int rr = 0; rr < 4; ++rr) bsrc[rr] = Bbase + (long)(rr * 64 + rA) * K + g8;

#define STAGE_A(bufp, rr, k0)                                                  \
  __builtin_amdgcn_global_load_lds(                                            \
      (const __attribute__((address_space(1))) void*)(A + asrc[rr] + (k0)),    \
      (__attribute__((address_space(3))) void*)((bufp) + (rr) * 4096 + wave * 512), \
      16, 0, 0)
#define STAGE_B(bufp, rr, k0)                                                  \
  __builtin_amdgcn_global_load_lds(                                            \
      (const __attribute__((address_space(1))) void*)(Bw + bsrc[rr] + (k0)),   \
      (__attribute__((address_space(3))) void*)((bufp) + (rr) * 4096 + wave * 512), \
      16, 0, 0)
#define STAGE_TILE(T)                                                          \
  {                                                                            \
    u16* sA_ = ldsA + ((T) & 1) * ASZ;                                         \
    u16* sB_ = ldsB + ((T) & 1) * BSZ;                                         \
    const int k0_ = (T) << 6;                                                  \
    STAGE_A(sA_, 0, k0_); STAGE_A(sA_, 1, k0_);                                \
    STAGE_B(sB_, 0, k0_); STAGE_B(sB_, 1, k0_);                                \
    STAGE_B(sB_, 2, k0_); STAGE_B(sB_, 3, k0_);                                \
  }
#define READ_FRAGS(F, T)                                                       \
  {                                                                            \
    u16* rA_ = ldsA + ((T) & 1) * ASZ;                                         \
    u16* rB_ = ldsB + ((T) & 1) * BSZ;                                         \
    _Pragma("unroll") for (int m = 0; m < 4; ++m)                              \
    _Pragma("unroll") for (int ks = 0; ks < 2; ++ks)                           \
      F.a[m][ks] = *reinterpret_cast<const bf16x8*>(&rA_[aoff[m][ks]]);        \
    _Pragma("unroll") for (int n = 0; n < 4; ++n)                              \
    _Pragma("unroll") for (int ks = 0; ks < 2; ++ks)                           \
      F.b[n][ks] = *reinterpret_cast<const bf16x8*>(&rB_[boff[n][ks]]);        \
  }
#define RA_ITER(T, FC, FN)                                                     \
  {                                                                            \
    if ((T) + 2 < NT) STAGE_TILE((T) + 2)                                      \
    if ((T) + 1 < NT) {                                                        \
      if ((T) + 2 < NT) asm volatile("s_waitcnt vmcnt(6)" ::: "memory");       \
      else              asm volatile("s_waitcnt vmcnt(0)" ::: "memory");       \
      __builtin_amdgcn_s_barrier();                                            \
      READ_FRAGS(FN, (T) + 1)                                                  \
      __builtin_amdgcn_s_barrier();                                            \
    }                                                                          \
    __builtin_amdgcn_s_setprio(1);                                             \
    _Pragma("unroll") for (int ks = 0; ks < 2; ++ks)                           \
    _Pragma("unroll") for (int m = 0; m < 4; ++m)                              \
    _Pragma("unroll") for (int n = 0; n < 4; ++n)                              \
      acc[m][n] = __builtin_amdgcn_mfma_f32_16x16x32_bf16(                     \
          FC.a[m][ks], FC.b[n][ks], acc[m][n], 0, 0, 0);                       \
    __builtin_amdgcn_s_setprio(0);                                             \
  }

  const int NT = K >> 6;

  f32x4 acc[4][4] = {};
  Frags fA, fB;

  STAGE_TILE(0)
  STAGE_TILE(1)
  asm volatile("s_waitcnt vmcnt(6)" ::: "memory");
  __builtin_amdgcn_s_barrier();
  READ_FRAGS(fA, 0)
  asm volatile("s_waitcnt lgkmcnt(0)" ::: "memory");
  __builtin_amdgcn_sched_barrier(0);
  __builtin_amdgcn_s_barrier();

  for (int t = 0; t < NT; t += 2) {
    RA_ITER(t, fA, fB)
    RA_ITER(t + 1, fB, fA)
  }
#undef STAGE_A
#undef STAGE_B
#undef STAGE_TILE
#undef READ_FRAGS
#undef RA_ITER

  const long cbase = bz * batchC;
  const int crow = by * 128;
  const int ccol = bx * 256;
  constexpr bool obf = (MODE == 1);
#pragma unroll
  for (int m = 0; m < 4; ++m) {
    const int qm = m >> 1, ml = m & 1;
    const int r0 = crow + qm * 64 + wr * 32 + ml * 16 + hi * 4;
#pragma unroll
    for (int n = 0; n < 4; ++n) {
      const int qn = n >> 1, nl = n & 1;
      const int c = ccol + qn * 128 + wc * 32 + nl * 16 + fr;
      const float bb = bias ? bias[c] : 0.0f;
#pragma unroll
      for (int j = 0; j < 4; ++j) {
        float v = acc[m][n][j] + bb;
        if (relu) v = fmaxf(v, 0.0f);
        const long idx = cbase + (long)(r0 + j) * N + c;
        if (obf) ((u16*)Cout)[idx] = f2bf(v);
        else     ((float*)Cout)[idx] = v;
      }
    }
  }
}

// ---------------------------------------------------------------------------
extern "C" void kernel_launch(void* const* d_in, const int* in_sizes, int n_in,
                              void* d_out, int out_size, void* d_ws, size_t ws_size,
                              hipStream_t stream) {
  (void)in_sizes; (void)n_in; (void)out_size; (void)ws_size;
  const float* x  = (const float*)d_in[0];
  const float* Wq = (const float*)d_in[1];
  const float* bq = (const float*)d_in[2];
  const float* Wk = (const float*)d_in[3];
  const float* bk = (const float*)d_in[4];
  const float* Wv = (const float*)d_in[5];
  const float* bv = (const float*)d_in[6];
  const float* W1 = (const float*)d_in[7];
  const float* b1 = (const float*)d_in[8];
  const float* W2 = (const float*)d_in[9];
  const float* b2 = (const float*)d_in[10];
  const float* W3 = (const float*)d_in[11];
  const float* b3 = (const float*)d_in[12];

  char* ws = (char*)d_ws;
  const size_t MB = 1u << 20;
  u16* Qbf  = (u16*)(ws + 0);
  u16* Kbf  = Qbf + 8388608;
  u16* h2   = (u16*)(ws + 0);
  u16* xbf = (u16*)(ws + 64 * MB);
  u16* Vbf = xbf + (size_t)8192 * 1024;
  u16* P   = (u16*)(ws + 64 * MB);
  u16* Wq_b = (u16*)(ws + 96 * MB);
  u16* Wk_b = Wq_b + 1048576;
  u16* Wv_b = Wk_b + 1048576;
  u16* W1_b = Wv_b + 1048576;
  u16* W2_b = W1_b + 1048576;
  u16* W3_b = W2_b + 4194304;
  u16* Qn = (u16*)(ws + 120 * MB);
  u16* Kn = Qn + 8388608;
  u16* Vt = Kn + 8388608;
  u16* attnout = Qn;
  u16* h1      = Kn;

  CastSegs cs;
  cs.src[0] = x;  cs.dst[0] = xbf;
  cs.src[1] = Wq; cs.dst[1] = Wq_b;
  cs.src[2] = Wk; cs.dst[2] = Wk_b;
  cs.src[3] = Wv; cs.dst[3] = Wv_b;
  cs.src[4] = W1; cs.dst[4] = W1_b;
  cs.src[5] = W2; cs.dst[5] = W2_b;
  cs.src[6] = W3; cs.dst[6] = W3_b;
  long szs[7] = {2097152, 262144, 262144, 262144, 262144, 1048576, 1048576};
  long acc0 = 0;
  for (int i = 0; i < 7; ++i) { cs.beg[i] = acc0; acc0 += szs[i]; }
  cs.beg[7] = acc0;
  cast_multi_kernel<<<dim3((unsigned)((acc0 + 255) / 256)), 256, 0, stream>>>(cs);

  // 2. fused QKV: M=8192, N=3072, K=1024 (256^2, grid 384, GBY=8)
  gemm256<2><<<dim3(12 * 32), 512, 0, stream>>>(
      xbf, Wq_b, bq, Qbf, bk, Kbf, bv, Vbf, 3072, 1024, 0, 0, 0, 0, 12, 32, 8);
  // 3. normalize + transpose
  l2norm2_kernel<<<16384, 256, 0, stream>>>(Qbf, Kbf, Qn, Kn);
  transpose_kernel<<<dim3(32, 64, 4), dim3(32, 8), 0, stream>>>(Vbf, Vt, 2048, 1024);
  // 4. sim = Qn @ Kn^T -> bf16 (256^2, grid 256, GBY=8)
  gemm256<1><<<dim3(8 * 8 * 4), 512, 0, stream>>>(
      Qn, Kn, nullptr, P, nullptr, nullptr, nullptr, nullptr,
      2048, 1024, 2097152L, 2097152L, 4194304L, 0, 8, 8, 8);
  // 5. softmax (bf16 in/out), in-place on P
  softmax_kernel<<<8192, 256, 0, stream>>>(P, P);
  // 6. attnout = P @ V (gemmra, grid 256, GBY=8)
  gemmra<1><<<dim3(4 * 16 * 4), 512, 0, stream>>>(
      P, Vt, nullptr, attnout, 1024, 2048, 4194304L, 2097152L, 2097152L, 0, 4, 16, 8);
  // 7. MLP
  gemmra<1><<<dim3(4 * 64), 512, 0, stream>>>(
      attnout, W1_b, b1, h1, 1024, 1024, 0, 0, 0, 1, 4, 64, 16);
  gemm256<1><<<dim3(16 * 32), 512, 0, stream>>>(
      h1, W2_b, b2, h2, nullptr, nullptr, nullptr, nullptr,
      4096, 1024, 0, 0, 0, 1, 16, 32, 8);
  gemmra<0><<<dim3(4 * 64), 512, 0, stream>>>(
      h2, W3_b, b3, (float*)d_out, 1024, 4096, 0, 0, 0, 0, 4, 64, 16);
}